// Round 3
// baseline (2514.928 us; speedup 1.0000x reference)
//
#include <hip/hip_runtime.h>

__device__ __forceinline__ float leaky(float x) { return x >= 0.f ? x : 0.1f * x; }

// ---------------- phase 1: histogram of src ----------------
__global__ __launch_bounds__(256) void hist_kernel(const int* __restrict__ edge_index,
                                                   int* __restrict__ hist, int E)
{
    int e = blockIdx.x * 256 + threadIdx.x;
    if (e < E) atomicAdd(&hist[edge_index[e]], 1);
}

// ---------------- phase 2: exclusive scan over N counters ----------------
__global__ __launch_bounds__(1024) void scan1_kernel(const int* __restrict__ hist,
                                                     int* __restrict__ offsets,
                                                     int* __restrict__ bsums, int N)
{
    __shared__ int wsum[16];
    int gid  = blockIdx.x * 1024 + threadIdx.x;
    int lane = threadIdx.x & 63, wid = threadIdx.x >> 6;
    int v = (gid < N) ? hist[gid] : 0;
    int inc = v;
#pragma unroll
    for (int d = 1; d < 64; d <<= 1) { int n = __shfl_up(inc, d); if (lane >= d) inc += n; }
    if (lane == 63) wsum[wid] = inc;
    __syncthreads();
    if (threadIdx.x < 16) {
        int t = wsum[threadIdx.x];
        int inc2 = t;
#pragma unroll
        for (int d = 1; d < 16; d <<= 1) { int n = __shfl_up(inc2, d); if ((int)threadIdx.x >= d) inc2 += n; }
        wsum[threadIdx.x] = inc2 - t;
        if (threadIdx.x == 15) bsums[blockIdx.x] = inc2;
    }
    __syncthreads();
    if (gid < N) offsets[gid] = inc - v + wsum[wid];
}

__global__ __launch_bounds__(64) void scan2_kernel(int* __restrict__ bsums, int nb)
{
    int lane = threadIdx.x;
    int carry = 0;
    for (int base = 0; base < nb; base += 64) {
        int i = base + lane;
        int v = (i < nb) ? bsums[i] : 0;
        int inc = v;
#pragma unroll
        for (int d = 1; d < 64; d <<= 1) { int n = __shfl_up(inc, d); if (lane >= d) inc += n; }
        if (i < nb) bsums[i] = inc - v + carry;
        carry += __shfl(inc, 63);
    }
}

__global__ __launch_bounds__(1024) void scan3_kernel(int* __restrict__ offsets,
                                                     int* __restrict__ cursor,
                                                     const int* __restrict__ bsums, int N)
{
    int gid = blockIdx.x * 1024 + threadIdx.x;
    if (gid < N) {
        int o = offsets[gid] + bsums[blockIdx.x];
        offsets[gid] = o;
        cursor[gid]  = o;
    }
}

// ---------------- phase 3: scatter (edge id, tgt) into sorted position ----------------
__global__ __launch_bounds__(256) void perm_kernel(const int* __restrict__ edge_index,
                                                   int* __restrict__ cursor,
                                                   int2* __restrict__ perm2, int E)
{
    int e = blockIdx.x * 256 + threadIdx.x;
    if (e >= E) return;
    int src = edge_index[e];
    int tgt = edge_index[E + e];
    int pos = atomicAdd(&cursor[src], 1);
    perm2[pos] = make_int2(e, tgt);
}

// ---------------- phase 4: fused gather + edge MLP + moments + node MLP ----------------
// one wave per node
__global__ __launch_bounds__(256) void mega_kernel(
    const float* __restrict__ x_t, const float* __restrict__ edge_attr,
    const int2* __restrict__ perm2,
    const int* __restrict__ offsets, const int* __restrict__ hist,
    const float* __restrict__ x_s, const float* __restrict__ u,
    const int* __restrict__ batch_s,
    const float* __restrict__ w1a, const float* __restrict__ b1a,
    const float* __restrict__ w2a, const float* __restrict__ b2a,
    const float* __restrict__ w1b, const float* __restrict__ b1b,
    const float* __restrict__ w2b, const float* __restrict__ b2b,
    float* __restrict__ out, int N)
{
    __shared__ float sw1[225], sw2[225], sb1[15], sb2[15];
    __shared__ float tw1[810], tw2[100], tb1[10], tb2[10];
    for (int i = threadIdx.x; i < 225; i += 256) { sw1[i] = w1a[i]; sw2[i] = w2a[i]; }
    for (int i = threadIdx.x; i < 810; i += 256) tw1[i] = w1b[i];
    for (int i = threadIdx.x; i < 100; i += 256) tw2[i] = w2b[i];
    if (threadIdx.x < 15) { sb1[threadIdx.x] = b1a[threadIdx.x]; sb2[threadIdx.x] = b2a[threadIdx.x]; }
    if (threadIdx.x < 10) { tb1[threadIdx.x] = b1b[threadIdx.x]; tb2[threadIdx.x] = b2b[threadIdx.x]; }
    __syncthreads();

    int node = (blockIdx.x * 256 + threadIdx.x) >> 6;
    int lane = threadIdx.x & 63;
    if (node >= N) return;

    int start = offsets[node];
    int cnt   = hist[node];

    float s1[15], s2[15], s3[15], s4[15];
#pragma unroll
    for (int f = 0; f < 15; f++) { s1[f] = 0.f; s2[f] = 0.f; s3[f] = 0.f; s4[f] = 0.f; }

    for (int k = lane; k < cnt; k += 64) {
        int2 pe = perm2[start + k];
        int e = pe.x, tgt = pe.y;

        float in[15];
        const float* xt = x_t + (size_t)tgt * 5;
#pragma unroll
        for (int q = 0; q < 5; q++) in[q] = xt[q];
        const float2* ea = (const float2*)(edge_attr + (size_t)e * 10);
#pragma unroll
        for (int q = 0; q < 5; q++) { float2 t = ea[q]; in[5 + 2 * q] = t.x; in[6 + 2 * q] = t.y; }

        float h[15];
#pragma unroll
        for (int j = 0; j < 15; j++) {
            float a = sb1[j];
#pragma unroll
            for (int i = 0; i < 15; i++) a = fmaf(in[i], sw1[i * 15 + j], a);
            h[j] = leaky(a);
        }
#pragma unroll
        for (int j = 0; j < 15; j++) {
            float y = sb2[j];
#pragma unroll
            for (int i = 0; i < 15; i++) y = fmaf(h[i], sw2[i * 15 + j], y);
            float y2 = y * y;
            s1[j] += y; s2[j] += y2; s3[j] += y2 * y; s4[j] += y2 * y2;
        }
    }

    // butterfly: all lanes end with full sums
#pragma unroll
    for (int d = 1; d < 64; d <<= 1) {
#pragma unroll
        for (int f = 0; f < 15; f++) {
            s1[f] += __shfl_xor(s1[f], d);
            s2[f] += __shfl_xor(s2[f], d);
            s3[f] += __shfl_xor(s3[f], d);
            s4[f] += __shfl_xor(s4[f], d);
        }
    }

    float cf  = (float)cnt;
    float inv = 1.0f / fmaxf(cf, 1.0f);

    // stats in-place: s1->mean, s2->std, s3->skew, s4->kurt
#pragma unroll
    for (int f = 0; f < 15; f++) {
        float m1 = s1[f] * inv;
        float m2 = s2[f] * inv;
        float m3 = s3[f] * inv;
        float m4 = s4[f] * inv;
        float var = fmaxf(m2 - m1 * m1, 0.0f);
        float sd  = sqrtf(var + 1e-6f);
        float m1sq = m1 * m1;
        float c3 = m3 - 3.0f * m1 * m2 + 2.0f * m1sq * m1;
        float c4 = m4 - 4.0f * m1 * m3 + 6.0f * m1sq * m2 - 3.0f * m1sq * m1sq;
        float is = 1.0f / sd;
        float is2 = is * is;
        s1[f] = m1;
        s2[f] = sd;
        s3[f] = c3 * is2 * is;
        s4[f] = c4 * is2 * is2;
    }

    // node MLP: lanes 0..9 each compute one output column
    float o1 = 0.f;
    if (lane < 10) {
        float a = tb1[lane];
        const float* xs = x_s + (size_t)node * 10;
#pragma unroll
        for (int q = 0; q < 10; q++) a = fmaf(xs[q], tw1[q * 10 + lane], a);
        a = fmaf(cf, tw1[100 + lane], a);
#pragma unroll
        for (int f = 0; f < 15; f++) {
            a = fmaf(s1[f], tw1[(11 + f) * 10 + lane], a);
            a = fmaf(s2[f], tw1[(26 + f) * 10 + lane], a);
            a = fmaf(s3[f], tw1[(41 + f) * 10 + lane], a);
            a = fmaf(s4[f], tw1[(56 + f) * 10 + lane], a);
        }
        int b = batch_s[node];
        const float* uu = u + (size_t)b * 10;
#pragma unroll
        for (int q = 0; q < 10; q++) a = fmaf(uu[q], tw1[(71 + q) * 10 + lane], a);
        o1 = leaky(a);
    }

    float o1v[10];
#pragma unroll
    for (int m = 0; m < 10; m++) o1v[m] = __shfl(o1, m);

    if (lane < 10) {
        float a = tb2[lane];
#pragma unroll
        for (int m = 0; m < 10; m++) a = fmaf(o1v[m], tw2[m * 10 + lane], a);
        out[(size_t)node * 10 + lane] = a;
    }
}

extern "C" void kernel_launch(void* const* d_in, const int* in_sizes, int n_in,
                              void* d_out, int out_size, void* d_ws, size_t ws_size,
                              hipStream_t stream)
{
    const float* x_s       = (const float*)d_in[0];
    const float* x_t       = (const float*)d_in[1];
    const float* edge_attr = (const float*)d_in[2];
    const float* u         = (const float*)d_in[3];
    const int*   edge_index= (const int*)d_in[4];
    const int*   batch_s   = (const int*)d_in[5];
    const float* w1a = (const float*)d_in[6];
    const float* b1a = (const float*)d_in[7];
    const float* w2a = (const float*)d_in[8];
    const float* b2a = (const float*)d_in[9];
    const float* w1b = (const float*)d_in[10];
    const float* b1b = (const float*)d_in[11];
    const float* w2b = (const float*)d_in[12];
    const float* b2b = (const float*)d_in[13];

    int N = in_sizes[0] / 10;   // N_S
    int E = in_sizes[2] / 10;   // edge_attr [E,10]
    int nb = (N + 1023) / 1024;

    // workspace: hist[N], offsets[N], cursor[N], bsums[1024], perm2[E] (int2)
    int*  hist    = (int*)d_ws;
    int*  offsets = hist + N;
    int*  cursor  = offsets + N;
    int*  bsums   = cursor + N;
    int2* perm2   = (int2*)(bsums + 1024);

    hipMemsetAsync(hist, 0, (size_t)N * sizeof(int), stream);

    hist_kernel<<<(E + 255) / 256, 256, 0, stream>>>(edge_index, hist, E);
    scan1_kernel<<<nb, 1024, 0, stream>>>(hist, offsets, bsums, N);
    scan2_kernel<<<1, 64, 0, stream>>>(bsums, nb);
    scan3_kernel<<<nb, 1024, 0, stream>>>(offsets, cursor, bsums, N);
    perm_kernel<<<(E + 255) / 256, 256, 0, stream>>>(edge_index, cursor, perm2, E);
    mega_kernel<<<(N + 3) / 4, 256, 0, stream>>>(
        x_t, edge_attr, perm2, offsets, hist,
        x_s, u, batch_s,
        w1a, b1a, w2a, b2a, w1b, b1b, w2b, b2b,
        (float*)d_out, N);
}

// Round 4
// 1038.117 us; speedup vs baseline: 2.4226x; 2.4226x over previous
//
#include <hip/hip_runtime.h>

#define NPB 6      // nodes per block in mega_kernel

__device__ __forceinline__ float leaky(float x) { return fmaxf(x, 0.1f * x); }

// ---------------- phase 1: histogram of src ----------------
__global__ __launch_bounds__(256) void hist_kernel(const int* __restrict__ edge_index,
                                                   int* __restrict__ hist, int E)
{
    int e = blockIdx.x * 256 + threadIdx.x;
    if (e < E) atomicAdd(&hist[edge_index[e]], 1);
}

// ---------------- phase 2: exclusive scan over N counters ----------------
__global__ __launch_bounds__(1024) void scan1_kernel(const int* __restrict__ hist,
                                                     int* __restrict__ offsets,
                                                     int* __restrict__ bsums, int N)
{
    __shared__ int wsum[16];
    int gid  = blockIdx.x * 1024 + threadIdx.x;
    int lane = threadIdx.x & 63, wid = threadIdx.x >> 6;
    int v = (gid < N) ? hist[gid] : 0;
    int inc = v;
#pragma unroll
    for (int d = 1; d < 64; d <<= 1) { int n = __shfl_up(inc, d); if (lane >= d) inc += n; }
    if (lane == 63) wsum[wid] = inc;
    __syncthreads();
    if (threadIdx.x < 16) {
        int t = wsum[threadIdx.x];
        int inc2 = t;
#pragma unroll
        for (int d = 1; d < 16; d <<= 1) { int n = __shfl_up(inc2, d); if ((int)threadIdx.x >= d) inc2 += n; }
        wsum[threadIdx.x] = inc2 - t;
        if (threadIdx.x == 15) bsums[blockIdx.x] = inc2;
    }
    __syncthreads();
    if (gid < N) offsets[gid] = inc - v + wsum[wid];
}

__global__ __launch_bounds__(64) void scan2_kernel(int* __restrict__ bsums, int nb)
{
    int lane = threadIdx.x;
    int carry = 0;
    for (int base = 0; base < nb; base += 64) {
        int i = base + lane;
        int v = (i < nb) ? bsums[i] : 0;
        int inc = v;
#pragma unroll
        for (int d = 1; d < 64; d <<= 1) { int n = __shfl_up(inc, d); if (lane >= d) inc += n; }
        if (i < nb) bsums[i] = inc - v + carry;
        carry += __shfl(inc, 63);
    }
}

__global__ __launch_bounds__(1024) void scan3_kernel(int* __restrict__ offsets,
                                                     int* __restrict__ cursor,
                                                     const int* __restrict__ bsums, int N)
{
    int gid = blockIdx.x * 1024 + threadIdx.x;
    if (gid < N) {
        int o = offsets[gid] + bsums[blockIdx.x];
        offsets[gid] = o;
        cursor[gid]  = o;
    }
}

// ---------------- phase 3: scatter (edge id, tgt) into sorted position ----------------
__global__ __launch_bounds__(256) void perm_kernel(const int* __restrict__ edge_index,
                                                   int* __restrict__ cursor,
                                                   int2* __restrict__ perm2, int E)
{
    int e = blockIdx.x * 256 + threadIdx.x;
    if (e >= E) return;
    int src = edge_index[e];
    int tgt = edge_index[E + e];
    int pos = atomicAdd(&cursor[src], 1);
    perm2[pos] = make_int2(e, tgt);
}

// ---------------- phase 4: fused gather + edge MLP + moments + node MLP ----------------
// block = 256 threads, owns NPB consecutive nodes (their sorted edges are contiguous).
__global__ __launch_bounds__(256) void mega_kernel(
    const float* __restrict__ x_t, const float* __restrict__ edge_attr,
    const int2* __restrict__ perm2, const int* __restrict__ offsets,
    const float* __restrict__ x_s, const float* __restrict__ u,
    const int* __restrict__ batch_s,
    const float* __restrict__ w1a, const float* __restrict__ b1a,
    const float* __restrict__ w2a, const float* __restrict__ b2a,
    const float* __restrict__ w1b, const float* __restrict__ b1b,
    const float* __restrict__ w2b, const float* __restrict__ b2b,
    float* __restrict__ out, int N, int E)
{
    __shared__ float ys[256 * 17];          // per-chunk edge outputs, stride 17 (bank spread)
    __shared__ float sw1[240], sw2[240];    // 15 rows x 16 (padded) for clean b128 reads
    __shared__ float sb1[16], sb2[16];
    __shared__ float tw1[810], tw2[100], tb1[16], tb2[16];
    __shared__ float accs[NPB * 64];        // [n]: [1+f]=S1 [16+f]=S2 [31+f]=S3 [46+f]=S4
    __shared__ float harr[NPB * 81];        // node MLP input rows
    __shared__ float o1s[NPB * 10];
    __shared__ int   nstart[NPB + 1];

    int tid = threadIdx.x;

    for (int i = tid; i < 240; i += 256) {
        int r = i >> 4, c = i & 15;
        sw1[i] = (c < 15) ? w1a[r * 15 + c] : 0.f;
        sw2[i] = (c < 15) ? w2a[r * 15 + c] : 0.f;
    }
    for (int i = tid; i < 810; i += 256) tw1[i] = w1b[i];
    for (int i = tid; i < 100; i += 256) tw2[i] = w2b[i];
    if (tid < 15) { sb1[tid] = b1a[tid]; sb2[tid] = b2a[tid]; }
    if (tid < 10) { tb1[tid] = b1b[tid]; tb2[tid] = b2b[tid]; }
    for (int i = tid; i < NPB * 64; i += 256) accs[i] = 0.f;

    int n0 = blockIdx.x * NPB;
    int nn = min(NPB, N - n0);
    if (tid <= nn) nstart[tid] = (n0 + tid < N) ? offsets[n0 + tid] : E;
    __syncthreads();

    int e_lo = nstart[0], e_hi = nstart[nn];
    int nchunks = (e_hi - e_lo + 255) >> 8;

    int f = tid & 15, sub = tid >> 4, lane = tid & 63;

    for (int c = 0; c < nchunks; ++c) {
        int base = e_lo + (c << 8);
        int ce = min(256, e_hi - base);

        // ---- phase A: one edge per thread, MLP into LDS ----
        if (tid < ce) {
            int2 pe = perm2[base + tid];
            int e = pe.x, tgt = pe.y;

            float in0[15];
            const float* xt = x_t + (size_t)tgt * 5;
#pragma unroll
            for (int q = 0; q < 5; q++) in0[q] = xt[q];
            const float2* ea = (const float2*)(edge_attr + (size_t)e * 10);
#pragma unroll
            for (int q = 0; q < 5; q++) { float2 t2 = ea[q]; in0[5 + 2 * q] = t2.x; in0[6 + 2 * q] = t2.y; }

            float h[15];
#pragma unroll
            for (int j = 0; j < 15; j++) h[j] = sb1[j];
#pragma unroll
            for (int i = 0; i < 15; i++)
#pragma unroll
                for (int j = 0; j < 15; j++) h[j] = fmaf(in0[i], sw1[i * 16 + j], h[j]);
#pragma unroll
            for (int j = 0; j < 15; j++) h[j] = leaky(h[j]);

            float y[15];
#pragma unroll
            for (int j = 0; j < 15; j++) y[j] = sb2[j];
#pragma unroll
            for (int i = 0; i < 15; i++)
#pragma unroll
                for (int j = 0; j < 15; j++) y[j] = fmaf(h[i], sw2[i * 16 + j], y[j]);
#pragma unroll
            for (int j = 0; j < 15; j++) ys[tid * 17 + j] = y[j];
        }
        __syncthreads();

        // ---- phase B: (feature, sub) threads accumulate moments from LDS ----
        for (int n = 0; n < nn; ++n) {
            int lo = max(nstart[n] - base, 0);
            int hi = min(nstart[n + 1] - base, ce);
            if (hi > lo) {
                float s1 = 0.f, s2 = 0.f, s3 = 0.f, s4 = 0.f;
                for (int k = lo + sub; k < hi; k += 16) {
                    float v = ys[k * 17 + f];
                    float v2 = v * v;
                    s1 += v; s2 += v2; s3 += v2 * v; s4 += v2 * v2;
                }
                s1 += __shfl_xor(s1, 16); s1 += __shfl_xor(s1, 32);
                s2 += __shfl_xor(s2, 16); s2 += __shfl_xor(s2, 32);
                s3 += __shfl_xor(s3, 16); s3 += __shfl_xor(s3, 32);
                s4 += __shfl_xor(s4, 16); s4 += __shfl_xor(s4, 32);
                if (lane < 16 && f < 15) {
                    atomicAdd(&accs[n * 64 + 1 + f],  s1);
                    atomicAdd(&accs[n * 64 + 16 + f], s2);
                    atomicAdd(&accs[n * 64 + 31 + f], s3);
                    atomicAdd(&accs[n * 64 + 46 + f], s4);
                }
            }
        }
        __syncthreads();   // protect ys before next chunk overwrites
    }

    // ---- stats into harr ----
    if (tid < nn * 16 && f < 15) {
        int n = tid >> 4;
        float cf  = (float)(nstart[n + 1] - nstart[n]);
        float inv = 1.0f / fmaxf(cf, 1.0f);
        float m1 = accs[n * 64 + 1 + f]  * inv;
        float m2 = accs[n * 64 + 16 + f] * inv;
        float m3 = accs[n * 64 + 31 + f] * inv;
        float m4 = accs[n * 64 + 46 + f] * inv;
        float var = fmaxf(m2 - m1 * m1, 0.0f);
        float sd  = sqrtf(var + 1e-6f);
        float m1sq = m1 * m1;
        float c3 = m3 - 3.0f * m1 * m2 + 2.0f * m1sq * m1;
        float c4 = m4 - 4.0f * m1 * m3 + 6.0f * m1sq * m2 - 3.0f * m1sq * m1sq;
        float is = 1.0f / sd;
        float is2 = is * is;
        harr[n * 81 + 11 + f] = m1;
        harr[n * 81 + 26 + f] = sd;
        harr[n * 81 + 41 + f] = c3 * is2 * is;
        harr[n * 81 + 56 + f] = c4 * is2 * is2;
    }
    if (tid < nn * 10) {
        int n = tid / 10, q = tid % 10;
        harr[n * 81 + q]      = x_s[(size_t)(n0 + n) * 10 + q];
        harr[n * 81 + 71 + q] = u[(size_t)batch_s[n0 + n] * 10 + q];
    }
    if (tid < nn) harr[tid * 81 + 10] = (float)(nstart[tid + 1] - nstart[tid]);
    __syncthreads();

    // ---- node MLP ----
    if (tid < nn * 10) {
        int n = tid / 10, k = tid % 10;
        float a = tb1[k];
#pragma unroll
        for (int j = 0; j < 81; j++) a = fmaf(harr[n * 81 + j], tw1[j * 10 + k], a);
        o1s[n * 10 + k] = leaky(a);
    }
    __syncthreads();
    if (tid < nn * 10) {
        int n = tid / 10, k = tid % 10;
        float a = tb2[k];
#pragma unroll
        for (int m = 0; m < 10; m++) a = fmaf(o1s[n * 10 + m], tw2[m * 10 + k], a);
        out[(size_t)(n0 + n) * 10 + k] = a;
    }
}

extern "C" void kernel_launch(void* const* d_in, const int* in_sizes, int n_in,
                              void* d_out, int out_size, void* d_ws, size_t ws_size,
                              hipStream_t stream)
{
    const float* x_s       = (const float*)d_in[0];
    const float* x_t       = (const float*)d_in[1];
    const float* edge_attr = (const float*)d_in[2];
    const float* u         = (const float*)d_in[3];
    const int*   edge_index= (const int*)d_in[4];
    const int*   batch_s   = (const int*)d_in[5];
    const float* w1a = (const float*)d_in[6];
    const float* b1a = (const float*)d_in[7];
    const float* w2a = (const float*)d_in[8];
    const float* b2a = (const float*)d_in[9];
    const float* w1b = (const float*)d_in[10];
    const float* b1b = (const float*)d_in[11];
    const float* w2b = (const float*)d_in[12];
    const float* b2b = (const float*)d_in[13];

    int N = in_sizes[0] / 10;   // N_S
    int E = in_sizes[2] / 10;   // edge_attr [E,10]
    int nb = (N + 1023) / 1024;

    // workspace: hist[N], offsets[N], cursor[N], bsums[1024], perm2[E] (int2)
    int*  hist    = (int*)d_ws;
    int*  offsets = hist + N;
    int*  cursor  = offsets + N;
    int*  bsums   = cursor + N;
    int2* perm2   = (int2*)(bsums + 1024);

    hipMemsetAsync(hist, 0, (size_t)N * sizeof(int), stream);

    hist_kernel<<<(E + 255) / 256, 256, 0, stream>>>(edge_index, hist, E);
    scan1_kernel<<<nb, 1024, 0, stream>>>(hist, offsets, bsums, N);
    scan2_kernel<<<1, 64, 0, stream>>>(bsums, nb);
    scan3_kernel<<<nb, 1024, 0, stream>>>(offsets, cursor, bsums, N);
    perm_kernel<<<(E + 255) / 256, 256, 0, stream>>>(edge_index, cursor, perm2, E);
    mega_kernel<<<(N + NPB - 1) / NPB, 256, 0, stream>>>(
        x_t, edge_attr, perm2, offsets,
        x_s, u, batch_s,
        w1a, b1a, w2a, b2a, w1b, b1b, w2b, b2b,
        (float*)d_out, N, E);
}

// Round 5
// 624.416 us; speedup vs baseline: 4.0277x; 1.6625x over previous
//
#include <hip/hip_runtime.h>

#define NPB 6            // nodes per block in mega_kernel
#define BN_SHIFT 8       // 256 nodes per bucket
#define NBMAX 512        // max buckets (N up to 131072)
#define CHUNK 4096       // edges per bin_kernel block

__device__ __forceinline__ float leaky(float x) { return fmaxf(x, 0.1f * x); }

// ---------------- K0: coarse bucket histogram (LDS-aggregated) ----------------
__global__ __launch_bounds__(256) void bhist_kernel(const int* __restrict__ src,
                                                    int* __restrict__ bhist, int E, int NB)
{
    __shared__ int h[NBMAX];
    for (int i = threadIdx.x; i < NB; i += 256) h[i] = 0;
    __syncthreads();
    int stride = gridDim.x * 256;
    for (int i = blockIdx.x * 256 + threadIdx.x; i < E; i += stride)
        atomicAdd(&h[src[i] >> BN_SHIFT], 1);
    __syncthreads();
    for (int i = threadIdx.x; i < NB; i += 256) if (h[i]) atomicAdd(&bhist[i], h[i]);
}

// ---------------- K1: scan bucket sizes -> bases & cursors ----------------
__global__ __launch_bounds__(64) void bscan_kernel(const int* __restrict__ bhist,
                                                   int* __restrict__ bbase,
                                                   int* __restrict__ bcur, int E, int NB)
{
    int lane = threadIdx.x;
    int carry = 0;
    for (int base = 0; base < NB; base += 64) {
        int i = base + lane;
        int v = (i < NB) ? bhist[i] : 0;
        int inc = v;
#pragma unroll
        for (int d = 1; d < 64; d <<= 1) { int m = __shfl_up(inc, d); if (lane >= d) inc += m; }
        if (i < NB) { bbase[i] = inc - v + carry; bcur[i] = inc - v + carry; }
        carry += __shfl(inc, 63);
    }
    if (lane == 0) bbase[NB] = E;
}

// ---------------- K2: bin pass — LDS sort 4096 edges by bucket, flush runs ----------------
__global__ __launch_bounds__(1024) void bin_kernel(const int* __restrict__ edge_index,
                                                   int* __restrict__ bcur,
                                                   int* __restrict__ bin_key,
                                                   int2* __restrict__ bin_pay, int E, int NB)
{
    __shared__ int s_src[CHUNK], s_e[CHUNK], s_tgt[CHUNK];
    __shared__ int hist[NBMAX], excl[NBMAX + 1], cur[NBMAX], baseg[NBMAX];
    int tid = threadIdx.x;
    int cbase = blockIdx.x * CHUNK;
    int n = min(CHUNK, E - cbase);

    for (int i = tid; i < NB; i += 1024) hist[i] = 0;
    __syncthreads();

    int msrc[4], mtgt[4];
#pragma unroll
    for (int q = 0; q < 4; q++) {
        int i = tid + q * 1024;
        if (i < n) {
            msrc[q] = edge_index[cbase + i];
            mtgt[q] = edge_index[E + cbase + i];
            atomicAdd(&hist[msrc[q] >> BN_SHIFT], 1);
        }
    }
    __syncthreads();

    if (tid < 64) {
        int carry = 0;
        for (int base = 0; base < NB; base += 64) {
            int i = base + tid;
            int v = (i < NB) ? hist[i] : 0;
            int inc = v;
#pragma unroll
            for (int d = 1; d < 64; d <<= 1) { int m = __shfl_up(inc, d); if (tid >= d) inc += m; }
            if (i < NB) { excl[i] = inc - v + carry; cur[i] = inc - v + carry; }
            carry += __shfl(inc, 63);
        }
        if (tid == 0) excl[NB] = n;
    }
    __syncthreads();

#pragma unroll
    for (int q = 0; q < 4; q++) {
        int i = tid + q * 1024;
        if (i < n) {
            int b = msrc[q] >> BN_SHIFT;
            int p = atomicAdd(&cur[b], 1);
            s_src[p] = msrc[q];
            s_e[p]   = cbase + i;
            s_tgt[p] = mtgt[q];
        }
    }
    __syncthreads();

    if (tid < NB) {
        int cnt = excl[tid + 1] - excl[tid];
        baseg[tid] = cnt ? atomicAdd(&bcur[tid], cnt) : 0;
    }
    __syncthreads();

#pragma unroll
    for (int q = 0; q < 4; q++) {
        int i = tid + q * 1024;
        if (i < n) {
            int s = s_src[i];
            int b = s >> BN_SHIFT;
            int gp = baseg[b] + (i - excl[b]);
            bin_key[gp] = s;
            bin_pay[gp] = make_int2(s_e[i], s_tgt[i]);
        }
    }
}

// ---------------- K3: within-bucket exact sort + node offsets ----------------
// one block per bucket; scatter window ~80 KB -> L2-merged writes
__global__ __launch_bounds__(512) void bsort_kernel(const int* __restrict__ bin_key,
                                                    const int2* __restrict__ bin_pay,
                                                    const int* __restrict__ bbase,
                                                    int* __restrict__ offsets,
                                                    int2* __restrict__ perm2, int N)
{
    __shared__ int hist[257], cur[256];
    int tid = threadIdx.x;
    int b = blockIdx.x;
    int node0 = b << BN_SHIFT;
    int lo = bbase[b], hi = bbase[b + 1];

    if (tid < 257) hist[tid] = 0;
    __syncthreads();
    for (int i = lo + tid; i < hi; i += 512) atomicAdd(&hist[bin_key[i] - node0], 1);
    __syncthreads();
    if (tid < 64) {
        int carry = 0;
        for (int base = 0; base < 256; base += 64) {
            int i = base + tid;
            int v = hist[i];
            int inc = v;
#pragma unroll
            for (int d = 1; d < 64; d <<= 1) { int m = __shfl_up(inc, d); if (tid >= d) inc += m; }
            cur[i] = inc - v + carry;
            carry += __shfl(inc, 63);
        }
    }
    __syncthreads();
    if (tid < 256) {
        int node = node0 + tid;
        if (node < N) offsets[node] = lo + cur[tid];
    }
    __syncthreads();
    for (int i = lo + tid; i < hi; i += 512) {
        int s = bin_key[i];
        int p = lo + atomicAdd(&cur[s - node0], 1);
        perm2[p] = bin_pay[i];
    }
}

// ---------------- K4: fused gather + edge MLP + moments + node MLP ----------------
// (byte-identical to round 4)
__global__ __launch_bounds__(256) void mega_kernel(
    const float* __restrict__ x_t, const float* __restrict__ edge_attr,
    const int2* __restrict__ perm2, const int* __restrict__ offsets,
    const float* __restrict__ x_s, const float* __restrict__ u,
    const int* __restrict__ batch_s,
    const float* __restrict__ w1a, const float* __restrict__ b1a,
    const float* __restrict__ w2a, const float* __restrict__ b2a,
    const float* __restrict__ w1b, const float* __restrict__ b1b,
    const float* __restrict__ w2b, const float* __restrict__ b2b,
    float* __restrict__ out, int N, int E)
{
    __shared__ float ys[256 * 17];
    __shared__ float sw1[240], sw2[240];
    __shared__ float sb1[16], sb2[16];
    __shared__ float tw1[810], tw2[100], tb1[16], tb2[16];
    __shared__ float accs[NPB * 64];
    __shared__ float harr[NPB * 81];
    __shared__ float o1s[NPB * 10];
    __shared__ int   nstart[NPB + 1];

    int tid = threadIdx.x;

    for (int i = tid; i < 240; i += 256) {
        int r = i >> 4, c = i & 15;
        sw1[i] = (c < 15) ? w1a[r * 15 + c] : 0.f;
        sw2[i] = (c < 15) ? w2a[r * 15 + c] : 0.f;
    }
    for (int i = tid; i < 810; i += 256) tw1[i] = w1b[i];
    for (int i = tid; i < 100; i += 256) tw2[i] = w2b[i];
    if (tid < 15) { sb1[tid] = b1a[tid]; sb2[tid] = b2a[tid]; }
    if (tid < 10) { tb1[tid] = b1b[tid]; tb2[tid] = b2b[tid]; }
    for (int i = tid; i < NPB * 64; i += 256) accs[i] = 0.f;

    int n0 = blockIdx.x * NPB;
    int nn = min(NPB, N - n0);
    if (tid <= nn) nstart[tid] = (n0 + tid < N) ? offsets[n0 + tid] : E;
    __syncthreads();

    int e_lo = nstart[0], e_hi = nstart[nn];
    int nchunks = (e_hi - e_lo + 255) >> 8;

    int f = tid & 15, sub = tid >> 4, lane = tid & 63;

    for (int c = 0; c < nchunks; ++c) {
        int base = e_lo + (c << 8);
        int ce = min(256, e_hi - base);

        if (tid < ce) {
            int2 pe = perm2[base + tid];
            int e = pe.x, tgt = pe.y;

            float in0[15];
            const float* xt = x_t + (size_t)tgt * 5;
#pragma unroll
            for (int q = 0; q < 5; q++) in0[q] = xt[q];
            const float2* ea = (const float2*)(edge_attr + (size_t)e * 10);
#pragma unroll
            for (int q = 0; q < 5; q++) { float2 t2 = ea[q]; in0[5 + 2 * q] = t2.x; in0[6 + 2 * q] = t2.y; }

            float h[15];
#pragma unroll
            for (int j = 0; j < 15; j++) h[j] = sb1[j];
#pragma unroll
            for (int i = 0; i < 15; i++)
#pragma unroll
                for (int j = 0; j < 15; j++) h[j] = fmaf(in0[i], sw1[i * 16 + j], h[j]);
#pragma unroll
            for (int j = 0; j < 15; j++) h[j] = leaky(h[j]);

            float y[15];
#pragma unroll
            for (int j = 0; j < 15; j++) y[j] = sb2[j];
#pragma unroll
            for (int i = 0; i < 15; i++)
#pragma unroll
                for (int j = 0; j < 15; j++) y[j] = fmaf(h[i], sw2[i * 16 + j], y[j]);
#pragma unroll
            for (int j = 0; j < 15; j++) ys[tid * 17 + j] = y[j];
        }
        __syncthreads();

        for (int n = 0; n < nn; ++n) {
            int lo = max(nstart[n] - base, 0);
            int hi = min(nstart[n + 1] - base, ce);
            if (hi > lo) {
                float s1 = 0.f, s2 = 0.f, s3 = 0.f, s4 = 0.f;
                for (int k = lo + sub; k < hi; k += 16) {
                    float v = ys[k * 17 + f];
                    float v2 = v * v;
                    s1 += v; s2 += v2; s3 += v2 * v; s4 += v2 * v2;
                }
                s1 += __shfl_xor(s1, 16); s1 += __shfl_xor(s1, 32);
                s2 += __shfl_xor(s2, 16); s2 += __shfl_xor(s2, 32);
                s3 += __shfl_xor(s3, 16); s3 += __shfl_xor(s3, 32);
                s4 += __shfl_xor(s4, 16); s4 += __shfl_xor(s4, 32);
                if (lane < 16 && f < 15) {
                    atomicAdd(&accs[n * 64 + 1 + f],  s1);
                    atomicAdd(&accs[n * 64 + 16 + f], s2);
                    atomicAdd(&accs[n * 64 + 31 + f], s3);
                    atomicAdd(&accs[n * 64 + 46 + f], s4);
                }
            }
        }
        __syncthreads();
    }

    if (tid < nn * 16 && f < 15) {
        int n = tid >> 4;
        float cf  = (float)(nstart[n + 1] - nstart[n]);
        float inv = 1.0f / fmaxf(cf, 1.0f);
        float m1 = accs[n * 64 + 1 + f]  * inv;
        float m2 = accs[n * 64 + 16 + f] * inv;
        float m3 = accs[n * 64 + 31 + f] * inv;
        float m4 = accs[n * 64 + 46 + f] * inv;
        float var = fmaxf(m2 - m1 * m1, 0.0f);
        float sd  = sqrtf(var + 1e-6f);
        float m1sq = m1 * m1;
        float c3 = m3 - 3.0f * m1 * m2 + 2.0f * m1sq * m1;
        float c4 = m4 - 4.0f * m1 * m3 + 6.0f * m1sq * m2 - 3.0f * m1sq * m1sq;
        float is = 1.0f / sd;
        float is2 = is * is;
        harr[n * 81 + 11 + f] = m1;
        harr[n * 81 + 26 + f] = sd;
        harr[n * 81 + 41 + f] = c3 * is2 * is;
        harr[n * 81 + 56 + f] = c4 * is2 * is2;
    }
    if (tid < nn * 10) {
        int n = tid / 10, q = tid % 10;
        harr[n * 81 + q]      = x_s[(size_t)(n0 + n) * 10 + q];
        harr[n * 81 + 71 + q] = u[(size_t)batch_s[n0 + n] * 10 + q];
    }
    if (tid < nn) harr[tid * 81 + 10] = (float)(nstart[tid + 1] - nstart[tid]);
    __syncthreads();

    if (tid < nn * 10) {
        int n = tid / 10, k = tid % 10;
        float a = tb1[k];
#pragma unroll
        for (int j = 0; j < 81; j++) a = fmaf(harr[n * 81 + j], tw1[j * 10 + k], a);
        o1s[n * 10 + k] = leaky(a);
    }
    __syncthreads();
    if (tid < nn * 10) {
        int n = tid / 10, k = tid % 10;
        float a = tb2[k];
#pragma unroll
        for (int m = 0; m < 10; m++) a = fmaf(o1s[n * 10 + m], tw2[m * 10 + k], a);
        out[(size_t)(n0 + n) * 10 + k] = a;
    }
}

extern "C" void kernel_launch(void* const* d_in, const int* in_sizes, int n_in,
                              void* d_out, int out_size, void* d_ws, size_t ws_size,
                              hipStream_t stream)
{
    const float* x_s       = (const float*)d_in[0];
    const float* x_t       = (const float*)d_in[1];
    const float* edge_attr = (const float*)d_in[2];
    const float* u         = (const float*)d_in[3];
    const int*   edge_index= (const int*)d_in[4];
    const int*   batch_s   = (const int*)d_in[5];
    const float* w1a = (const float*)d_in[6];
    const float* b1a = (const float*)d_in[7];
    const float* w2a = (const float*)d_in[8];
    const float* b2a = (const float*)d_in[9];
    const float* w1b = (const float*)d_in[10];
    const float* b1b = (const float*)d_in[11];
    const float* w2b = (const float*)d_in[12];
    const float* b2b = (const float*)d_in[13];

    int N = in_sizes[0] / 10;   // N_S
    int E = in_sizes[2] / 10;   // edge_attr [E,10]
    int NB = (N + (1 << BN_SHIFT) - 1) >> BN_SHIFT;   // buckets of 256 nodes

    // workspace layout (256-B aligned regions)
    char* p = (char*)d_ws;
    auto take = [&](size_t bytes) { char* r = p; p += (bytes + 255) & ~(size_t)255; return r; };
    int*  bhist   = (int*)take((size_t)NBMAX * 4);
    int*  bbase   = (int*)take((size_t)(NBMAX + 1) * 4);
    int*  bcur    = (int*)take((size_t)NBMAX * 4);
    int*  offsets = (int*)take((size_t)N * 4);
    int*  bin_key = (int*)take((size_t)E * 4);
    int2* bin_pay = (int2*)take((size_t)E * 8);
    int2* perm2   = (int2*)take((size_t)E * 8);

    hipMemsetAsync(bhist, 0, (size_t)NB * sizeof(int), stream);

    bhist_kernel<<<512, 256, 0, stream>>>(edge_index, bhist, E, NB);
    bscan_kernel<<<1, 64, 0, stream>>>(bhist, bbase, bcur, E, NB);
    bin_kernel<<<(E + CHUNK - 1) / CHUNK, 1024, 0, stream>>>(
        edge_index, bcur, bin_key, bin_pay, E, NB);
    bsort_kernel<<<NB, 512, 0, stream>>>(bin_key, bin_pay, bbase, offsets, perm2, N);
    mega_kernel<<<(N + NPB - 1) / NPB, 256, 0, stream>>>(
        x_t, edge_attr, perm2, offsets,
        x_s, u, batch_s,
        w1a, b1a, w2a, b2a, w1b, b1b, w2b, b2b,
        (float*)d_out, N, E);
}